// Round 2
// baseline (1406.999 us; speedup 1.0000x reference)
//
#include <hip/hip_runtime.h>
#include <stdint.h>

typedef __attribute__((ext_vector_type(8))) short short8;
typedef __attribute__((ext_vector_type(8))) unsigned short ushort8;
typedef __attribute__((ext_vector_type(4))) float f32x4;
typedef __attribute__((ext_vector_type(2))) float f32x2;

#define N_TOT 131072L
#define D_DIM 512
#define K_PROT 256

static __device__ __forceinline__ unsigned short bf16_rne(float f) {
  unsigned u = __float_as_uint(f);
  u += 0x7FFFu + ((u >> 16) & 1u);
  return (unsigned short)(u >> 16);
}
static __device__ __forceinline__ float bf16_f(unsigned short h) {
  return __uint_as_float(((unsigned)h) << 16);
}

// ---------------------------------------------------------------------------
// K0: normalize prototypes; emit bf16 hi/lo split in two layouts:
//   ph/pl : [16 dc][256 k][32 dl]   (k-major rows, 32-d chunks)  for GEMM1 B
//   pth/ptl: [8 kc][512 d][32 kl]   (d-major rows, 32-k chunks)  for GEMM2 B
// ---------------------------------------------------------------------------
__global__ __launch_bounds__(128) void prep_p(
    const float* __restrict__ p,
    unsigned short* __restrict__ ph, unsigned short* __restrict__ pl,
    unsigned short* __restrict__ pth, unsigned short* __restrict__ ptl) {
  const int k = blockIdx.x, t = threadIdx.x;
  f32x4 v = *(const f32x4*)(p + k * 512 + t * 4);
  float ss = v[0]*v[0] + v[1]*v[1] + v[2]*v[2] + v[3]*v[3];
#pragma unroll
  for (int m2 = 1; m2 < 64; m2 <<= 1) ss += __shfl_xor(ss, m2, 64);
  __shared__ float red[2];
  if ((t & 63) == 0) red[t >> 6] = ss;
  __syncthreads();
  float inv = 1.0f / fmaxf(sqrtf(red[0] + red[1]), 1e-12f);
#pragma unroll
  for (int e = 0; e < 4; ++e) {
    int d = t * 4 + e;
    float pn = v[e] * inv;
    unsigned short h = bf16_rne(pn);
    unsigned short l = bf16_rne(pn - bf16_f(h));
    ph[(d >> 5) * (256 * 32) + k * 32 + (d & 31)] = h;
    pl[(d >> 5) * (256 * 32) + k * 32 + (d & 31)] = l;
    pth[(k >> 5) * (512 * 32) + d * 32 + (k & 31)] = h;
    ptl[(k >> 5) * (512 * 32) + d * 32 + (k & 31)] = l;
  }
}

// ---------------------------------------------------------------------------
// K1: sims = (z @ p_norm^T) * 10/||z||  (split-bf16 MFMA), then sparsemax
//     (Michelot fixed point), write weights fp32 to d_out, inv_norm to ws.
// Block: 512 thr (8 waves), 256 rows/block. Wave (rg,cg) owns
// [128 rows][64 cols]: 8 rt x 4 ct tiles of 16x16, acc = 128 VGPR.
// LDS (64KB, phase-overlaid):
//   GEMM phase: zbh@0 zbl@16K pbh@32K pbl@48K  ([256][32] bf16 each, swizzled)
//   sparsemax:  invbuf@0(1K) taubuf@1K(1K) part@2K(8K)
// ---------------------------------------------------------------------------
__global__ __launch_bounds__(512, 2) void k1_gemm_sparsemax(
    const float* __restrict__ z, const unsigned short* __restrict__ ph,
    const unsigned short* __restrict__ pl, float* __restrict__ wout,
    float* __restrict__ invn) {
  __shared__ char smem[65536];
  unsigned short* zbh = (unsigned short*)(smem);
  unsigned short* zbl = (unsigned short*)(smem + 16384);
  unsigned short* pbh = (unsigned short*)(smem + 32768);
  unsigned short* pbl = (unsigned short*)(smem + 49152);

  const int t = threadIdx.x;
  const int lane = t & 63, wv = t >> 6;
  const int m = lane & 15, g = lane >> 4;
  const int rg = wv >> 2, cg = wv & 3;
  const long rows0 = (long)blockIdx.x * 256;

  f32x4 acc[8][4];
#pragma unroll
  for (int a = 0; a < 8; ++a)
#pragma unroll
    for (int b = 0; b < 4; ++b) acc[a][b] = (f32x4){0.f, 0.f, 0.f, 0.f};

  const int srow = t >> 1;          // staging row (0..255)
  const int sd16 = (t & 1) * 16;    // staging d offset within 32-chunk
  float ssq = 0.f;

  for (int dc = 0; dc < 16; ++dc) {
    if (dc) __syncthreads();
    // ---- stage z chunk: fp32 -> (hi,lo) bf16, accumulate sumsq ----
    {
      const float* zp = z + (rows0 + srow) * 512 + dc * 32 + sd16;
      f32x4 a0 = *(const f32x4*)(zp);
      f32x4 a1 = *(const f32x4*)(zp + 4);
      f32x4 a2 = *(const f32x4*)(zp + 8);
      f32x4 a3 = *(const f32x4*)(zp + 12);
      ushort8 h0, h1, l0, l1;
#pragma unroll
      for (int e = 0; e < 4; ++e) {
        float f; unsigned short hh;
        f = a0[e]; ssq += f * f; hh = bf16_rne(f); h0[e]     = hh; l0[e]     = bf16_rne(f - bf16_f(hh));
        f = a1[e]; ssq += f * f; hh = bf16_rne(f); h0[e + 4] = hh; l0[e + 4] = bf16_rne(f - bf16_f(hh));
        f = a2[e]; ssq += f * f; hh = bf16_rne(f); h1[e]     = hh; l1[e]     = bf16_rne(f - bf16_f(hh));
        f = a3[e]; ssq += f * f; hh = bf16_rne(f); h1[e + 4] = hh; l1[e + 4] = bf16_rne(f - bf16_f(hh));
      }
      int base = srow * 64;
      int sw = (srow & 3) << 4;
      int s0 = (sd16 * 2) ^ sw;
      int s1 = (sd16 * 2 + 16) ^ sw;
      *(ushort8*)((char*)zbh + base + s0) = h0;
      *(ushort8*)((char*)zbh + base + s1) = h1;
      *(ushort8*)((char*)zbl + base + s0) = l0;
      *(ushort8*)((char*)zbl + base + s1) = l1;
    }
    // ---- stage p chunk (already bf16 hi/lo in ws) ----
    {
      const char* srcH = (const char*)(ph + dc * 8192);
      const char* srcL = (const char*)(pl + dc * 8192);
#pragma unroll
      for (int q = 0; q < 2; ++q) {
        int idx = t * 2 + q;                     // 0..1023 16B chunks
        int kcol = idx >> 2;
        int off = (idx & 3) * 16;
        int dsw = kcol * 64 + (off ^ ((kcol & 3) << 4));
        *(f32x4*)((char*)pbh + dsw) = *(const f32x4*)(srcH + idx * 16);
        *(f32x4*)((char*)pbl + dsw) = *(const f32x4*)(srcL + idx * 16);
      }
    }
    __syncthreads();
    // ---- MFMA: acc += zhi*phi + zlo*phi + zhi*plo ----
#pragma unroll
    for (int rth = 0; rth < 2; ++rth) {
      short8 ah[4], al[4];
#pragma unroll
      for (int r4 = 0; r4 < 4; ++r4) {
        int row = rg * 128 + (rth * 4 + r4) * 16 + m;
        int ab = row * 64 + ((g * 16) ^ ((m & 3) << 4));
        ah[r4] = *(const short8*)((char*)zbh + ab);
        al[r4] = *(const short8*)((char*)zbl + ab);
      }
#pragma unroll
      for (int ct = 0; ct < 4; ++ct) {
        int col = cg * 64 + ct * 16 + m;
        int bb = col * 64 + ((g * 16) ^ ((m & 3) << 4));
        short8 bh = *(const short8*)((char*)pbh + bb);
        short8 bl = *(const short8*)((char*)pbl + bb);
#pragma unroll
        for (int r4 = 0; r4 < 4; ++r4) {
          int rt = rth * 4 + r4;
          acc[rt][ct] = __builtin_amdgcn_mfma_f32_16x16x32_bf16(ah[r4], bh, acc[rt][ct], 0, 0, 0);
          acc[rt][ct] = __builtin_amdgcn_mfma_f32_16x16x32_bf16(al[r4], bh, acc[rt][ct], 0, 0, 0);
          acc[rt][ct] = __builtin_amdgcn_mfma_f32_16x16x32_bf16(ah[r4], bl, acc[rt][ct], 0, 0, 0);
        }
      }
    }
  }

  // ---- row norms (each row's d-range was covered by thread pair (2r,2r+1)) --
  float ssq2 = ssq + __shfl_xor(ssq, 1, 64);
  __syncthreads();  // GEMM LDS dead; overlay sparsemax buffers
  float* invbuf = (float*)smem;            // 256 f
  float* taubuf = (float*)(smem + 1024);   // 256 f
  float* part   = (float*)(smem + 2048);   // 256*4*2 f
  if ((t & 1) == 0) {
    float iv = 1.0f / fmaxf(sqrtf(ssq2), 1e-12f);
    invbuf[srow] = iv;
    invn[rows0 + srow] = iv;
  }
  if (t < 256) taubuf[t] = -3.0e38f;
  __syncthreads();

  // ---- scale: logits = raw_dot * inv_norm * TEMPERATURE ----
#pragma unroll
  for (int rt = 0; rt < 8; ++rt)
#pragma unroll
    for (int i = 0; i < 4; ++i) {
      int rowb = rg * 128 + rt * 16 + g * 4 + i;
      float sc = invbuf[rowb] * 10.0f;
#pragma unroll
      for (int ct = 0; ct < 4; ++ct) acc[rt][ct][i] *= sc;
    }

  // ---- Michelot sparsemax threshold iteration ----
  for (int it = 0; it < 20; ++it) {
#pragma unroll
    for (int rt = 0; rt < 8; ++rt)
#pragma unroll
      for (int i = 0; i < 4; ++i) {
        int rowb = rg * 128 + rt * 16 + g * 4 + i;
        float tv = taubuf[rowb];
        float s = 0.f, c = 0.f;
#pragma unroll
        for (int ct = 0; ct < 4; ++ct) {
          float v = acc[rt][ct][i];
          bool gt = v > tv;
          s += gt ? v : 0.f;
          c += gt ? 1.f : 0.f;
        }
#pragma unroll
        for (int mk = 1; mk < 16; mk <<= 1) {
          s += __shfl_xor(s, mk, 64);
          c += __shfl_xor(c, mk, 64);
        }
        if (m == 0) *(f32x2*)&part[(rowb * 4 + cg) * 2] = (f32x2){s, c};
      }
    __syncthreads();
    int changed = 0;
    if (t < 256) {
      f32x4 p0 = *(const f32x4*)&part[t * 8];
      f32x4 p1 = *(const f32x4*)&part[t * 8 + 4];
      float S = p0[0] + p0[2] + p1[0] + p1[2];
      float C = p0[1] + p0[3] + p1[1] + p1[3];
      float tn = (S - 1.0f) / C;
      changed = (tn != taubuf[t]);
      taubuf[t] = tn;
    }
    if (!__syncthreads_or(changed)) break;
  }

  // ---- weights = max(logit - tau, 0), write fp32 to d_out ----
#pragma unroll
  for (int rt = 0; rt < 8; ++rt)
#pragma unroll
    for (int i = 0; i < 4; ++i) {
      int rowb = rg * 128 + rt * 16 + g * 4 + i;
      float tv = taubuf[rowb];
      long base = (rows0 + rowb) * 256 + cg * 64 + m;
#pragma unroll
      for (int ct = 0; ct < 4; ++ct)
        wout[base + ct * 16] = fmaxf(acc[rt][ct][i] - tv, 0.f);
    }
}

// ---------------------------------------------------------------------------
// K2: recon = weights @ p_norm (split-bf16 MFMA), residual = z*inv - recon.
// Block: 512 thr, 256 rows. dh loop over two 256-wide d halves.
// LDS (64KB): tbh@0 tbl@16K ([256 dloc][32 k]), wbh@32K wbl@48K ([256 row][32 k])
// ---------------------------------------------------------------------------
__global__ __launch_bounds__(512, 2) void k2_gemm2(
    const float* __restrict__ z, const float* __restrict__ wmat,
    const unsigned short* __restrict__ pth, const unsigned short* __restrict__ ptl,
    const float* __restrict__ invn, float* __restrict__ recon,
    float* __restrict__ resid) {
  __shared__ char smem[65536];
  unsigned short* tbh = (unsigned short*)(smem);
  unsigned short* tbl = (unsigned short*)(smem + 16384);
  unsigned short* wbh = (unsigned short*)(smem + 32768);
  unsigned short* wbl = (unsigned short*)(smem + 49152);

  const int t = threadIdx.x;
  const int lane = t & 63, wv = t >> 6;
  const int m = lane & 15, g = lane >> 4;
  const int rg = wv >> 2, cg = wv & 3;
  const long rows0 = (long)blockIdx.x * 256;

  const int srow = t >> 1;
  const int sk16 = (t & 1) * 16;

  for (int dh = 0; dh < 2; ++dh) {
    f32x4 acc[8][4];
#pragma unroll
    for (int a = 0; a < 8; ++a)
#pragma unroll
      for (int b = 0; b < 4; ++b) acc[a][b] = (f32x4){0.f, 0.f, 0.f, 0.f};

    for (int kc = 0; kc < 8; ++kc) {
      if (dh || kc) __syncthreads();
      // ---- stage weights chunk fp32 -> hi/lo bf16 ----
      {
        const float* wp = wmat + (rows0 + srow) * 256 + kc * 32 + sk16;
        f32x4 a0 = *(const f32x4*)(wp);
        f32x4 a1 = *(const f32x4*)(wp + 4);
        f32x4 a2 = *(const f32x4*)(wp + 8);
        f32x4 a3 = *(const f32x4*)(wp + 12);
        ushort8 h0, h1, l0, l1;
#pragma unroll
        for (int e = 0; e < 4; ++e) {
          float f; unsigned short hh;
          f = a0[e]; hh = bf16_rne(f); h0[e]     = hh; l0[e]     = bf16_rne(f - bf16_f(hh));
          f = a1[e]; hh = bf16_rne(f); h0[e + 4] = hh; l0[e + 4] = bf16_rne(f - bf16_f(hh));
          f = a2[e]; hh = bf16_rne(f); h1[e]     = hh; l1[e]     = bf16_rne(f - bf16_f(hh));
          f = a3[e]; hh = bf16_rne(f); h1[e + 4] = hh; l1[e + 4] = bf16_rne(f - bf16_f(hh));
        }
        int base = srow * 64;
        int sw = (srow & 3) << 4;
        int s0 = (sk16 * 2) ^ sw;
        int s1 = (sk16 * 2 + 16) ^ sw;
        *(ushort8*)((char*)wbh + base + s0) = h0;
        *(ushort8*)((char*)wbh + base + s1) = h1;
        *(ushort8*)((char*)wbl + base + s0) = l0;
        *(ushort8*)((char*)wbl + base + s1) = l1;
      }
      // ---- stage p^T half-chunk: d rows used this dh ----
      {
        int dloc = t >> 1;  // 0..255 block-local d
        int kk16 = (t & 1) * 16;
        int dglob = (dloc >> 6) * 128 + dh * 64 + (dloc & 63);
        const unsigned short* sH = pth + kc * 16384 + dglob * 32 + kk16;
        const unsigned short* sL = ptl + kc * 16384 + dglob * 32 + kk16;
        int base = dloc * 64;
        int sw = (dloc & 3) << 4;
        int s0 = (kk16 * 2) ^ sw;
        int s1 = (kk16 * 2 + 16) ^ sw;
        *(f32x4*)((char*)tbh + base + s0) = *(const f32x4*)(sH);
        *(f32x4*)((char*)tbh + base + s1) = *(const f32x4*)(sH + 8);
        *(f32x4*)((char*)tbl + base + s0) = *(const f32x4*)(sL);
        *(f32x4*)((char*)tbl + base + s1) = *(const f32x4*)(sL + 8);
      }
      __syncthreads();
      // ---- MFMA ----
#pragma unroll
      for (int rth = 0; rth < 2; ++rth) {
        short8 ah[4], al[4];
#pragma unroll
        for (int r4 = 0; r4 < 4; ++r4) {
          int row = rg * 128 + (rth * 4 + r4) * 16 + m;
          int ab = row * 64 + ((g * 16) ^ ((m & 3) << 4));
          ah[r4] = *(const short8*)((char*)wbh + ab);
          al[r4] = *(const short8*)((char*)wbl + ab);
        }
#pragma unroll
        for (int ct = 0; ct < 4; ++ct) {
          int dl_ = cg * 64 + ct * 16 + m;
          int bb = dl_ * 64 + ((g * 16) ^ ((m & 3) << 4));
          short8 bh = *(const short8*)((char*)tbh + bb);
          short8 bl = *(const short8*)((char*)tbl + bb);
#pragma unroll
          for (int r4 = 0; r4 < 4; ++r4) {
            int rt = rth * 4 + r4;
            acc[rt][ct] = __builtin_amdgcn_mfma_f32_16x16x32_bf16(ah[r4], bh, acc[rt][ct], 0, 0, 0);
            acc[rt][ct] = __builtin_amdgcn_mfma_f32_16x16x32_bf16(al[r4], bh, acc[rt][ct], 0, 0, 0);
            acc[rt][ct] = __builtin_amdgcn_mfma_f32_16x16x32_bf16(ah[r4], bl, acc[rt][ct], 0, 0, 0);
          }
        }
      }
    }
    // ---- epilogue: recon + residual for this d half ----
#pragma unroll
    for (int rt = 0; rt < 8; ++rt)
#pragma unroll
      for (int i = 0; i < 4; ++i) {
        int rowb = rg * 128 + rt * 16 + g * 4 + i;
        long row = rows0 + rowb;
        float iv = invn[row];
#pragma unroll
        for (int ct = 0; ct < 4; ++ct) {
          int dcol = cg * 128 + dh * 64 + ct * 16 + m;
          long o = row * 512 + dcol;
          float rc = acc[rt][ct][i];
          recon[o] = rc;
          resid[o] = z[o] * iv - rc;
        }
      }
  }
}

// ---------------------------------------------------------------------------
extern "C" void kernel_launch(void* const* d_in, const int* in_sizes, int n_in,
                              void* d_out, int out_size, void* d_ws, size_t ws_size,
                              hipStream_t stream) {
  const float* z = (const float*)d_in[0];
  const float* p = (const float*)d_in[1];
  float* out = (float*)d_out;
  float* recon = out;                                   // [N,512]
  float* wout  = out + N_TOT * 512;                     // [N,256]
  float* resid = out + N_TOT * 512 + N_TOT * 256;       // [N,512]

  char* ws = (char*)d_ws;
  float* invn          = (float*)ws;                    // 512 KB
  unsigned short* ph   = (unsigned short*)(ws + 524288);            // 256 KB
  unsigned short* pl   = (unsigned short*)(ws + 524288 + 262144);   // 256 KB
  unsigned short* pth  = (unsigned short*)(ws + 524288 + 524288);   // 256 KB
  unsigned short* ptl  = (unsigned short*)(ws + 524288 + 786432);   // 256 KB

  prep_p<<<dim3(256), dim3(128), 0, stream>>>(p, ph, pl, pth, ptl);
  k1_gemm_sparsemax<<<dim3(512), dim3(512), 0, stream>>>(z, ph, pl, wout, invn);
  k2_gemm2<<<dim3(512), dim3(512), 0, stream>>>(z, wout, pth, ptl, invn, recon, resid);
}